// Round 1
// baseline (228.799 us; speedup 1.0000x reference)
//
#include <hip/hip_runtime.h>

// SpikeCountLayer: out[b,s,h,w] = #{t : in[b,t,h,w]==s}
// Shapes fixed by setup_inputs(): B=32 (derived), T=1024, H*W=1024, dim_s=32.
//
// Strategy: memory-bound streaming histogram.
//  - 512 blocks (B*16), 512 threads. Block owns 64 contiguous pixels x all T.
//  - thread = (tq = tid>>6 in [0,8), pixlane = tid&63). Wave reads 256 B
//    contiguous per t-step -> fully coalesced, zero over-fetch.
//  - per-THREAD private histogram in LDS, layout hist[val*512 + tid]:
//    bank = tid%32 -> 2-way aliasing only (free on gfx950, m136).
//    atomicAdd on shared emits ds_add_u32 (no-return): 1 LDS op/element.
//  - epilogue: reduce the 8 tq-partials per (s,pix) in-block, coalesced store.
//    No global atomics, no output pre-zeroing needed.

constexpr int T_DIM   = 1024;
constexpr int HW      = 1024;   // H*W
constexpr int DIM_S   = 32;
constexpr int PIX_PB  = 64;     // pixels per block
constexpr int TQ      = 8;      // t-slices (== waves per block)
constexpr int THREADS = PIX_PB * TQ;          // 512
constexpr int T_PER_THREAD = T_DIM / TQ;      // 128
constexpr int PLANE_CHUNKS = HW / PIX_PB;     // 16

__global__ __launch_bounds__(THREADS) void spike_hist_kernel(
    const int* __restrict__ in, int* __restrict__ out) {
    __shared__ int hist[DIM_S * THREADS];     // 64 KiB: [s][tid]

    const int tid = threadIdx.x;

    // zero LDS (harness poisons nothing in LDS, but it's uninitialized)
    #pragma unroll
    for (int k = 0; k < DIM_S; ++k) hist[k * THREADS + tid] = 0;
    __syncthreads();

    const int blk  = blockIdx.x;              // [0, B*16)
    const int b    = blk >> 4;
    const int pix0 = (blk & (PLANE_CHUNKS - 1)) * PIX_PB;
    const int pixlane = tid & (PIX_PB - 1);
    const int tq      = tid >> 6;             // wave index in block

    const int* __restrict__ p = in
        + (size_t)b * (T_DIM * HW)
        + (size_t)(tq * T_PER_THREAD) * HW
        + pix0 + pixlane;

    // main streaming loop: 128 coalesced dword loads per thread
    #pragma unroll 8
    for (int i = 0; i < T_PER_THREAD; ++i) {
        const int v = p[(size_t)i * HW];
        atomicAdd(&hist[v * THREADS + tid], 1);   // ds_add_u32, bank=tid%32
    }
    __syncthreads();

    // epilogue: 2048 outputs/block; out[b, s, pix0+pix] = sum over tq partials
    int* __restrict__ outb = out + (size_t)b * (DIM_S * HW) + pix0;
    #pragma unroll
    for (int e = tid; e < DIM_S * PIX_PB; e += THREADS) {
        const int pix = e & (PIX_PB - 1);
        const int s   = e >> 6;
        int sum = 0;
        #pragma unroll
        for (int q = 0; q < TQ; ++q)
            sum += hist[s * THREADS + q * PIX_PB + pix];
        outb[(size_t)s * HW + pix] = sum;         // coalesced 256 B per wave
    }
}

extern "C" void kernel_launch(void* const* d_in, const int* in_sizes, int n_in,
                              void* d_out, int out_size, void* d_ws, size_t ws_size,
                              hipStream_t stream) {
    const int* in = (const int*)d_in[0];
    int* out      = (int*)d_out;
    const int B   = in_sizes[0] / (T_DIM * HW);   // 32 for the reference setup
    const int grid = B * PLANE_CHUNKS;            // 512 blocks
    spike_hist_kernel<<<grid, THREADS, 0, stream>>>(in, out);
}

// Round 2
// 193.613 us; speedup vs baseline: 1.1817x; 1.1817x over previous
//
#include <hip/hip_runtime.h>

// SpikeCountLayer: out[b,s,h,w] = #{t : in[b,t,h,w]==s}
// B=32 (derived), T=1024, H*W=1024, dim_s=32.
//
// R1: LDS atomics (ds_add_u32) were the R0 bottleneck (~109 cyc/wave-atomic;
// 93 us at 9.6% HBM, 2.7% VALU). They were also unnecessary: the histogram
// column was thread-private. New scheme: per-thread 32-bin histogram packed
// as BYTES in 8 VGPRs (max count 128 < 256). Main loop is pure
// global_load_dword + ~27 VALU/element; zero LDS traffic. LDS only in the
// epilogue (plain ds_write/ds_read, 16 KiB/block).

constexpr int T_DIM   = 1024;
constexpr int HW      = 1024;   // H*W
constexpr int DIM_S   = 32;
constexpr int PIX_PB  = 64;     // pixels per block
constexpr int TQ      = 8;      // t-slices (== waves per block)
constexpr int THREADS = PIX_PB * TQ;          // 512
constexpr int T_PER_THREAD = T_DIM / TQ;      // 128  (byte counters safe)
constexpr int PLANE_CHUNKS = HW / PIX_PB;     // 16

__global__ __launch_bounds__(THREADS) void spike_hist_kernel(
    const int* __restrict__ in, int* __restrict__ out) {
    // [word j][tid]: thread tid's byte-packed counts for bins 4j..4j+3
    __shared__ int lds_w[8][THREADS];         // 16 KiB

    const int tid  = threadIdx.x;
    const int blk  = blockIdx.x;              // [0, B*16)
    const int b    = blk >> 4;
    const int pix0 = (blk & (PLANE_CHUNKS - 1)) * PIX_PB;
    const int pix  = tid & (PIX_PB - 1);
    const int tq   = tid >> 6;                // wave index in block

    const int* __restrict__ p = in
        + (size_t)b * (T_DIM * HW)
        + (size_t)(tq * T_PER_THREAD) * HW
        + pix0 + pix;

    // per-thread histogram: 32 bins, byte-packed into 8 dwords
    unsigned w[8] = {0u, 0u, 0u, 0u, 0u, 0u, 0u, 0u};

    #pragma unroll 8
    for (int i = 0; i < T_PER_THREAD; ++i) {
        const int v = p[(size_t)i * HW];              // coalesced 256 B/wave
        const unsigned inc = 1u << ((v & 3) << 3);    // byte lane within word
        const int sel = v >> 2;                       // which word
        #pragma unroll
        for (int j = 0; j < 8; ++j)
            w[j] += (sel == j) ? inc : 0u;            // cmp+cndmask+add
    }

    #pragma unroll
    for (int j = 0; j < 8; ++j) lds_w[j][tid] = (int)w[j];
    __syncthreads();

    // epilogue: 2048 outputs/block, 4 per thread.
    // out[b, s, pix0+opix] = sum over tq of byte (s&3) of word (s>>2)
    int* __restrict__ outb = out + (size_t)b * (DIM_S * HW) + pix0;
    #pragma unroll
    for (int r = 0; r < 4; ++r) {
        const int e    = r * THREADS + tid;   // [0, 2048)
        const int opix = e & (PIX_PB - 1);
        const int s    = e >> 6;              // uniform across each wave
        const int word = s >> 2;
        const int sh   = (s & 3) << 3;
        int sum = 0;
        #pragma unroll
        for (int q = 0; q < TQ; ++q)
            sum += (int)(((unsigned)lds_w[word][q * PIX_PB + opix] >> sh) & 0xFFu);
        outb[(size_t)s * HW + opix] = sum;    // coalesced 256 B/wave
    }
}

extern "C" void kernel_launch(void* const* d_in, const int* in_sizes, int n_in,
                              void* d_out, int out_size, void* d_ws, size_t ws_size,
                              hipStream_t stream) {
    const int* in = (const int*)d_in[0];
    int* out      = (int*)d_out;
    const int B   = in_sizes[0] / (T_DIM * HW);   // 32 for the reference setup
    const int grid = B * PLANE_CHUNKS;            // 512 blocks
    spike_hist_kernel<<<grid, THREADS, 0, stream>>>(in, out);
}